// Round 1
// baseline (724.347 us; speedup 1.0000x reference)
//
#include <hip/hip_runtime.h>
#include <math.h>

#define EPS 1e-6f
#define NB 4096
#define NN 64

// ---------------------------------------------------------------------------
// Transpose W1 [256][114] -> W1T [128][256] (rows 114..127 zero)
//           W2 [128][256] -> W2T [256][128]
// ---------------------------------------------------------------------------
__global__ void w_transpose_kernel(const float* __restrict__ W1,
                                   const float* __restrict__ W2,
                                   float* __restrict__ W1T,
                                   float* __restrict__ W2T) {
  int t = blockIdx.x * blockDim.x + threadIdx.x;
  if (t < 128 * 256) {
    int k = t >> 8, o = t & 255;
    W1T[t] = (k < 114) ? W1[o * 114 + k] : 0.0f;
  } else {
    int t2 = t - 128 * 256;
    if (t2 < 256 * 128) {
      int k = t2 >> 7, o = t2 & 127;
      W2T[t2] = W2[o * 256 + k];
    }
  }
}

// ---------------------------------------------------------------------------
// Er net: one thread per batch row.
// ---------------------------------------------------------------------------
__global__ void er_kernel(const float* __restrict__ ego_y,
                          const float* __restrict__ W_sel, const float* __restrict__ b_sel,
                          const float* __restrict__ W_s0,  const float* __restrict__ b_s0,
                          const float* __restrict__ W_map, const float* __restrict__ b_map,
                          const float* __restrict__ W_efc, const float* __restrict__ b_efc,
                          float* __restrict__ out) {
  int b = blockIdx.x * blockDim.x + threadIdx.x;
  if (b >= NB) return;
  const float lane[4] = {13.55f, 17.45f, 21.12f, 24.91f};
  float ego = ego_y[b];
  float dy[4];
#pragma unroll
  for (int j = 0; j < 4; j++) dy[j] = lane[j] - ego;

  // selector softmax
  float t[4];
#pragma unroll
  for (int i = 0; i < 4; i++) {
    float a = b_sel[i];
#pragma unroll
    for (int j = 0; j < 4; j++) a = fmaf(W_sel[i * 4 + j], dy[j], a);
    t[i] = a;
  }
  float m = fmaxf(fmaxf(t[0], t[1]), fmaxf(t[2], t[3]));
  float e[4], s = 0.f;
#pragma unroll
  for (int i = 0; i < 4; i++) { e[i] = expf(t[i] - m); s += e[i]; }
  float x[4];
#pragma unroll
  for (int i = 0; i < 4; i++) x[i] = (e[i] / s) * dy[i];

  // _auge(x, W_s0[8][4], b_s0)
  float f[48];
  float sn[8];
#pragma unroll
  for (int k = 0; k < 8; k++) {
    float a = b_s0[k];
#pragma unroll
    for (int j = 0; j < 4; j++) a = fmaf(W_s0[k * 4 + j], x[j], a);
    sn[k] = sinf(a) + EPS;
  }
#pragma unroll
  for (int i = 0; i < 4; i++) f[i] = x[i];
#pragma unroll
  for (int k = 0; k < 8; k++) f[4 + k] = sn[k];
#pragma unroll
  for (int i = 0; i < 4; i++) {
    float q = x[i] * x[i] + EPS;
    f[12 + i] = q; f[36 + i] = 1.0f / q;
  }
#pragma unroll
  for (int i = 0; i < 4; i++) {
    float c3 = (x[i] * x[i]) * x[i] + EPS;
    f[16 + i] = c3; f[40 + i] = 1.0f / c3;
  }
#pragma unroll
  for (int i = 0; i < 4; i++) {
    float ex = expf(x[i]) + EPS;
    f[20 + i] = ex; f[44 + i] = 1.0f / ex;
  }
#pragma unroll
  for (int i = 0; i < 4; i++) f[24 + i] = 1.0f / (x[i] + EPS);
#pragma unroll
  for (int k = 0; k < 8; k++) f[28 + k] = 1.0f / sn[k];

  // map 48 -> 8, leaky
  float y[8];
#pragma unroll
  for (int i = 0; i < 8; i++) {
    float a = b_map[i];
    for (int k = 0; k < 48; k++) a = fmaf(W_map[i * 48 + k], f[k], a);
    y[i] = (a >= 0.f) ? a : 0.1f * a;
  }
  // 8 -> 2
#pragma unroll
  for (int c = 0; c < 2; c++) {
    float a = b_efc[c];
#pragma unroll
    for (int i = 0; i < 8; i++) a = fmaf(W_efc[c * 8 + i], y[i], a);
    out[b * 4 + c] = a;
  }
}

// ---------------------------------------------------------------------------
// En net: one block (512 threads) per batch b. fp32 register-blocked LDS GEMMs.
// LDS: nin[128][64] (K-major features, zero-padded K), wc (32KB chunk region,
// reused as h2T[128][64]), h1[256][68] (padded), en_s[64][2].
// ---------------------------------------------------------------------------
__global__ __launch_bounds__(512, 1)
void en_kernel(const float* __restrict__ Pn, const float* __restrict__ Pego,
               const float* __restrict__ Vn, const float* __restrict__ Vego,
               const float* __restrict__ Cn,
               const float* __restrict__ W_s1, const float* __restrict__ b_s1,
               const float* __restrict__ b1, const float* __restrict__ b2,
               const float* __restrict__ W3, const float* __restrict__ b3,
               const float* __restrict__ Ww, const float* __restrict__ bw,
               const float* __restrict__ W1T, const float* __restrict__ W2T,
               float* __restrict__ out) {
  __shared__ float nin[128 * 64];   // [k][r]
  __shared__ float wc[64 * 128];    // weight chunk / h2T region (32 KB)
  __shared__ float h1[256 * 68];    // [o][r], stride 68 (pad)
  __shared__ float en_s[NN * 2];

  const int b = blockIdx.x;
  const int tid = threadIdx.x;

  // ---------------- phase 0: build features (K-major) ----------------
  if (tid < 128) {
    const int r = tid & 63;
    const bool isV = tid >= 64;
    const float* Pb = isV ? Vn : Pn;
    const float* Eb = isV ? Vego : Pego;
    const int c0 = isV ? 56 : 0;
    float p0 = Pb[(b * NN + r) * 2 + 0], p1 = Pb[(b * NN + r) * 2 + 1];
    float e0 = Eb[b * 2 + 0], e1 = Eb[b * 2 + 1];
    float d0 = p0 - e0, d1 = p1 - e1;
    nin[(c0 + 0) * 64 + r] = e0; nin[(c0 + 1) * 64 + r] = e1;
    nin[(c0 + 2) * 64 + r] = p0; nin[(c0 + 3) * 64 + r] = p1;
    nin[(c0 + 4) * 64 + r] = d0; nin[(c0 + 5) * 64 + r] = d1;
    const int a0 = c0 + 6;
    nin[(a0 + 0) * 64 + r] = d0; nin[(a0 + 1) * 64 + r] = d1;
    float s[17];
#pragma unroll
    for (int i = 0; i < 17; i++) {
      float arg = fmaf(W_s1[i * 2 + 0], d0, fmaf(W_s1[i * 2 + 1], d1, b_s1[i]));
      s[i] = sinf(arg) + EPS;
      nin[(a0 + 2 + i) * 64 + r] = s[i];
    }
    float q0 = d0 * d0 + EPS, q1 = d1 * d1 + EPS;
    float c30 = (d0 * d0) * d0 + EPS, c31 = (d1 * d1) * d1 + EPS;
    float ex0 = expf(d0) + EPS, ex1 = expf(d1) + EPS;
    nin[(a0 + 19) * 64 + r] = q0;  nin[(a0 + 20) * 64 + r] = q1;
    nin[(a0 + 21) * 64 + r] = c30; nin[(a0 + 22) * 64 + r] = c31;
    nin[(a0 + 23) * 64 + r] = ex0; nin[(a0 + 24) * 64 + r] = ex1;
    nin[(a0 + 25) * 64 + r] = 1.0f / (d0 + EPS);
    nin[(a0 + 26) * 64 + r] = 1.0f / (d1 + EPS);
#pragma unroll
    for (int i = 0; i < 17; i++) nin[(a0 + 27 + i) * 64 + r] = 1.0f / s[i];
    nin[(a0 + 44) * 64 + r] = 1.0f / q0;  nin[(a0 + 45) * 64 + r] = 1.0f / q1;
    nin[(a0 + 46) * 64 + r] = 1.0f / c30; nin[(a0 + 47) * 64 + r] = 1.0f / c31;
    nin[(a0 + 48) * 64 + r] = 1.0f / ex0; nin[(a0 + 49) * 64 + r] = 1.0f / ex1;
  } else if (tid < 192) {
    const int r = tid - 128;
    nin[112 * 64 + r] = Cn[(b * NN + r) * 2 + 0];
    nin[113 * 64 + r] = Cn[(b * NN + r) * 2 + 1];
  } else if (tid < 256) {
    const int r = tid - 192;
#pragma unroll
    for (int c = 114; c < 128; c++) nin[c * 64 + r] = 0.0f;  // zero K-pad
  }

  // ---------------- layer 1: 114(pad128) -> 256, leaky ----------------
  const int g = tid & 63;     // outputs o = 4g..4g+3  (lane index)
  const int rg = tid >> 6;    // wave id: rows 8rg..8rg+7
  float acc[4][8];
#pragma unroll
  for (int i = 0; i < 4; i++)
#pragma unroll
    for (int j = 0; j < 8; j++) acc[i][j] = 0.f;

  for (int ch = 0; ch < 4; ++ch) {
    const int k0 = ch * 32;
    // stage W1T rows k0..k0+31 -> wc [32][256]
    for (int idx = tid; idx < 32 * 64; idx += 512)
      ((float4*)wc)[idx] = ((const float4*)(W1T + k0 * 256))[idx];
    __syncthreads();
#pragma unroll 2
    for (int kk = 0; kk < 32; ++kk) {
      const int k = k0 + kk;
      float4 w  = *(const float4*)&wc[kk * 256 + 4 * g];
      float4 n0 = *(const float4*)&nin[k * 64 + 8 * rg];
      float4 n1 = *(const float4*)&nin[k * 64 + 8 * rg + 4];
      const float wv[4] = {w.x, w.y, w.z, w.w};
      const float nv[8] = {n0.x, n0.y, n0.z, n0.w, n1.x, n1.y, n1.z, n1.w};
#pragma unroll
      for (int i = 0; i < 4; i++)
#pragma unroll
        for (int j = 0; j < 8; j++)
          acc[i][j] = fmaf(wv[i], nv[j], acc[i][j]);
    }
    __syncthreads();
  }
  {
    float4 bb = *(const float4*)&b1[4 * g];
    const float bv[4] = {bb.x, bb.y, bb.z, bb.w};
#pragma unroll
    for (int i = 0; i < 4; i++) {
      const int o = 4 * g + i;
#pragma unroll
      for (int j = 0; j < 8; j++) {
        float v = acc[i][j] + bv[i];
        v = (v >= 0.f) ? v : 0.1f * v;
        h1[o * 68 + 8 * rg + j] = v;
      }
    }
  }

  // ---------------- layer 2: 256 -> 128, leaky ----------------
  const int g2 = tid & 31;    // outputs o2 = 4g2..4g2+3
  const int rg2 = tid >> 5;   // rows 4rg2..4rg2+3
  float acc2[4][4];
#pragma unroll
  for (int i = 0; i < 4; i++)
#pragma unroll
    for (int j = 0; j < 4; j++) acc2[i][j] = 0.f;

  for (int ch = 0; ch < 4; ++ch) {
    const int k0 = ch * 64;
    for (int idx = tid; idx < 64 * 32; idx += 512)
      ((float4*)wc)[idx] = ((const float4*)(W2T + k0 * 128))[idx];
    __syncthreads();
#pragma unroll 4
    for (int kk = 0; kk < 64; ++kk) {
      const int k = k0 + kk;
      float4 w = *(const float4*)&wc[kk * 128 + 4 * g2];
      float4 n = *(const float4*)&h1[k * 68 + 4 * rg2];
      const float wv[4] = {w.x, w.y, w.z, w.w};
      const float nv[4] = {n.x, n.y, n.z, n.w};
#pragma unroll
      for (int i = 0; i < 4; i++)
#pragma unroll
        for (int j = 0; j < 4; j++)
          acc2[i][j] = fmaf(wv[i], nv[j], acc2[i][j]);
    }
    __syncthreads();
  }
  {
    float4 bb = *(const float4*)&b2[4 * g2];
    const float bv[4] = {bb.x, bb.y, bb.z, bb.w};
#pragma unroll
    for (int i = 0; i < 4; i++) {
      float4 v;
      float tmp[4];
#pragma unroll
      for (int j = 0; j < 4; j++) {
        float u = acc2[i][j] + bv[i];
        tmp[j] = (u >= 0.f) ? u : 0.1f * u;
      }
      v.x = tmp[0]; v.y = tmp[1]; v.z = tmp[2]; v.w = tmp[3];
      *(float4*)&wc[(4 * g2 + i) * 64 + 4 * rg2] = v;  // h2T [128][64]
    }
  }
  __syncthreads();

  // ---------------- layer 3: 128 -> 2 ----------------
  if (tid < 128) {
    const int c = tid >> 6, r = tid & 63;
    float a = b3[c];
#pragma unroll 8
    for (int k = 0; k < 128; k++)
      a = fmaf(wc[k * 64 + r], W3[c * 128 + k], a);
    en_s[r * 2 + c] = a;
  }
  __syncthreads();

  // ---------------- logits + softmax over 64 neighbors + reduce ----------------
  if (tid < 64) {
    const int r = tid;
    float E0 = en_s[r * 2 + 0], E1 = en_s[r * 2 + 1];
    float pn0 = nin[2 * 64 + r], pn1 = nin[3 * 64 + r];
    float dp0 = nin[4 * 64 + r], dp1 = nin[5 * 64 + r];
    float logit = bw[0];
    logit = fmaf(E0, Ww[0], logit);
    logit = fmaf(E1, Ww[1], logit);
    logit = fmaf(pn0, Ww[2], logit);
    logit = fmaf(pn1, Ww[3], logit);
    logit = fmaf(dp0, Ww[4], logit);
    logit = fmaf(dp1, Ww[5], logit);
    float m = logit;
#pragma unroll
    for (int off = 32; off > 0; off >>= 1) m = fmaxf(m, __shfl_xor(m, off));
    float e = expf(logit - m);
    float ssum = e;
#pragma unroll
    for (int off = 32; off > 0; off >>= 1) ssum += __shfl_xor(ssum, off);
    float w = e / ssum;
    float o0 = w * E0, o1 = w * E1;
#pragma unroll
    for (int off = 32; off > 0; off >>= 1) {
      o0 += __shfl_xor(o0, off);
      o1 += __shfl_xor(o1, off);
    }
    if (r == 0) {
      out[b * 4 + 2] = o0;
      out[b * 4 + 3] = o1;
    }
  }
}

// ---------------------------------------------------------------------------
extern "C" void kernel_launch(void* const* d_in, const int* in_sizes, int n_in,
                              void* d_out, int out_size, void* d_ws, size_t ws_size,
                              hipStream_t stream) {
  const float* ego_y = (const float*)d_in[0];
  const float* Pn    = (const float*)d_in[1];
  const float* Pego  = (const float*)d_in[2];
  const float* Vn    = (const float*)d_in[3];
  const float* Vego  = (const float*)d_in[4];
  const float* Cn    = (const float*)d_in[5];
  const float* W_sel = (const float*)d_in[6];
  const float* b_sel = (const float*)d_in[7];
  const float* W_s0  = (const float*)d_in[8];
  const float* b_s0  = (const float*)d_in[9];
  const float* W_map = (const float*)d_in[10];
  const float* b_map = (const float*)d_in[11];
  const float* W_efc = (const float*)d_in[12];
  const float* b_efc = (const float*)d_in[13];
  const float* W_s1  = (const float*)d_in[14];
  const float* b_s1  = (const float*)d_in[15];
  const float* W1    = (const float*)d_in[16];
  const float* b1    = (const float*)d_in[17];
  const float* W2    = (const float*)d_in[18];
  const float* b2    = (const float*)d_in[19];
  const float* W3    = (const float*)d_in[20];
  const float* b3    = (const float*)d_in[21];
  const float* Ww    = (const float*)d_in[22];
  const float* bw    = (const float*)d_in[23];
  float* out = (float*)d_out;

  float* W1T = (float*)d_ws;             // [128][256]
  float* W2T = W1T + 128 * 256;          // [256][128]

  w_transpose_kernel<<<256, 256, 0, stream>>>(W1, W2, W1T, W2T);
  er_kernel<<<NB / 256, 256, 0, stream>>>(ego_y, W_sel, b_sel, W_s0, b_s0,
                                          W_map, b_map, W_efc, b_efc, out);
  en_kernel<<<NB, 512, 0, stream>>>(Pn, Pego, Vn, Vego, Cn, W_s1, b_s1,
                                    b1, b2, W3, b3, Ww, bw, W1T, W2T, out);
}

// Round 2
// 333.241 us; speedup vs baseline: 2.1736x; 2.1736x over previous
//
#include <hip/hip_runtime.h>
#include <math.h>

#define EPS 1e-6f
#define NB 4096
#define NN 64

typedef __attribute__((ext_vector_type(8))) short short8_t;
typedef __attribute__((ext_vector_type(4))) short short4_t;
typedef __attribute__((ext_vector_type(4))) float f32x4;

__device__ __forceinline__ unsigned short f2bf(float x) {
  unsigned u = __float_as_uint(x);
  u = u + 0x7fffu + ((u >> 16) & 1u);
  return (unsigned short)(u >> 16);
}
__device__ __forceinline__ float bf2f(unsigned short h) {
  return __uint_as_float(((unsigned)h) << 16);
}

// ---------------------------------------------------------------------------
// Pre-gather weights into MFMA fragment-major images (bf16 hi/lo planes).
// W1F: [p][mt 0..15][ks 0..3][lane][j]  (k>=114 zero-padded), plane stride 32768
// W2F: [p][mt 0..7 ][ks 0..7][lane][j],                        plane stride 32768
// value = W[m = mt*16 + (l&15)][k = ks*32 + (l>>4)*8 + j]
// ---------------------------------------------------------------------------
__global__ void w_prep_kernel(const float* __restrict__ W1,
                              const float* __restrict__ W2,
                              short* __restrict__ W1F,
                              short* __restrict__ W2F) {
  int t = blockIdx.x * blockDim.x + threadIdx.x;
  if (t >= 4096) return;
  {
    int l = t & 63, ks = (t >> 6) & 3, mt = t >> 8;  // mt 0..15
    int m = mt * 16 + (l & 15);
#pragma unroll
    for (int j = 0; j < 8; j++) {
      int k = ks * 32 + (l >> 4) * 8 + j;
      float x = (k < 114) ? W1[m * 114 + k] : 0.0f;
      unsigned short hh = f2bf(x);
      unsigned short ll = f2bf(x - bf2f(hh));
      int base = ((mt * 4 + ks) * 64 + l) * 8 + j;
      W1F[base] = (short)hh;
      W1F[32768 + base] = (short)ll;
    }
  }
  {
    int l = t & 63, ks = (t >> 6) & 7, mt = t >> 9;  // mt 0..7
    int m = mt * 16 + (l & 15);
#pragma unroll
    for (int j = 0; j < 8; j++) {
      int k = ks * 32 + (l >> 4) * 8 + j;
      float x = W2[m * 256 + k];
      unsigned short hh = f2bf(x);
      unsigned short ll = f2bf(x - bf2f(hh));
      int base = ((mt * 8 + ks) * 64 + l) * 8 + j;
      W2F[base] = (short)hh;
      W2F[32768 + base] = (short)ll;
    }
  }
}

// ---------------------------------------------------------------------------
// Er net: one thread per batch row (fp32, unchanged from passing baseline).
// ---------------------------------------------------------------------------
__global__ void er_kernel(const float* __restrict__ ego_y,
                          const float* __restrict__ W_sel, const float* __restrict__ b_sel,
                          const float* __restrict__ W_s0,  const float* __restrict__ b_s0,
                          const float* __restrict__ W_map, const float* __restrict__ b_map,
                          const float* __restrict__ W_efc, const float* __restrict__ b_efc,
                          float* __restrict__ out) {
  int b = blockIdx.x * blockDim.x + threadIdx.x;
  if (b >= NB) return;
  const float lane[4] = {13.55f, 17.45f, 21.12f, 24.91f};
  float ego = ego_y[b];
  float dy[4];
#pragma unroll
  for (int j = 0; j < 4; j++) dy[j] = lane[j] - ego;

  float t[4];
#pragma unroll
  for (int i = 0; i < 4; i++) {
    float a = b_sel[i];
#pragma unroll
    for (int j = 0; j < 4; j++) a = fmaf(W_sel[i * 4 + j], dy[j], a);
    t[i] = a;
  }
  float m = fmaxf(fmaxf(t[0], t[1]), fmaxf(t[2], t[3]));
  float e[4], s = 0.f;
#pragma unroll
  for (int i = 0; i < 4; i++) { e[i] = expf(t[i] - m); s += e[i]; }
  float x[4];
#pragma unroll
  for (int i = 0; i < 4; i++) x[i] = (e[i] / s) * dy[i];

  float f[48];
  float sn[8];
#pragma unroll
  for (int k = 0; k < 8; k++) {
    float a = b_s0[k];
#pragma unroll
    for (int j = 0; j < 4; j++) a = fmaf(W_s0[k * 4 + j], x[j], a);
    sn[k] = sinf(a) + EPS;
  }
#pragma unroll
  for (int i = 0; i < 4; i++) f[i] = x[i];
#pragma unroll
  for (int k = 0; k < 8; k++) f[4 + k] = sn[k];
#pragma unroll
  for (int i = 0; i < 4; i++) {
    float q = x[i] * x[i] + EPS;
    f[12 + i] = q; f[36 + i] = 1.0f / q;
  }
#pragma unroll
  for (int i = 0; i < 4; i++) {
    float c3 = (x[i] * x[i]) * x[i] + EPS;
    f[16 + i] = c3; f[40 + i] = 1.0f / c3;
  }
#pragma unroll
  for (int i = 0; i < 4; i++) {
    float ex = expf(x[i]) + EPS;
    f[20 + i] = ex; f[44 + i] = 1.0f / ex;
  }
#pragma unroll
  for (int i = 0; i < 4; i++) f[24 + i] = 1.0f / (x[i] + EPS);
#pragma unroll
  for (int k = 0; k < 8; k++) f[28 + k] = 1.0f / sn[k];

  float y[8];
#pragma unroll
  for (int i = 0; i < 8; i++) {
    float a = b_map[i];
    for (int k = 0; k < 48; k++) a = fmaf(W_map[i * 48 + k], f[k], a);
    y[i] = (a >= 0.f) ? a : 0.1f * a;
  }
#pragma unroll
  for (int c = 0; c < 2; c++) {
    float a = b_efc[c];
#pragma unroll
    for (int i = 0; i < 8; i++) a = fmaf(W_efc[c * 8 + i], y[i], a);
    out[b * 4 + c] = a;
  }
}

// ---------------------------------------------------------------------------
// En net: one block (512 thr, 8 waves) per batch. bf16 hi/lo 3-pass MFMA.
// fea: [64 r][128 k] bf16 x2 planes, XOR-swizzled (short idx ^ ((r&7)<<3))
// h1s: [64 r][256 k] bf16 x2 planes, same swizzle
// h2s: [128 o][64 r] fp32
// ---------------------------------------------------------------------------
__global__ __launch_bounds__(512, 2)
void en_kernel(const float* __restrict__ Pn, const float* __restrict__ Pego,
               const float* __restrict__ Vn, const float* __restrict__ Vego,
               const float* __restrict__ Cn,
               const float* __restrict__ W_s1, const float* __restrict__ b_s1,
               const float* __restrict__ b1, const float* __restrict__ b2,
               const float* __restrict__ W3, const float* __restrict__ b3,
               const float* __restrict__ Ww, const float* __restrict__ bw,
               const short* __restrict__ W1F, const short* __restrict__ W2F,
               float* __restrict__ out) {
  __shared__ __align__(16) short fea[2][64 * 128];
  __shared__ __align__(16) short h1s[2][64 * 256];
  __shared__ __align__(16) float h2s[128 * 64];
  __shared__ float stash[4 * 64];
  __shared__ float en_s[NN * 2];

  const int b = blockIdx.x;
  const int tid = threadIdx.x;
  const int w = tid >> 6;   // wave 0..7
  const int l = tid & 63;
  const int lr = l & 15;    // fragment row/col index
  const int lq = l >> 4;    // k-quad

  // ---- issue W1 fragment loads early (hidden under feature build) ----
  short8_t w1f[2][2][4];  // [plane][mt][ks]
#pragma unroll
  for (int p = 0; p < 2; p++)
#pragma unroll
    for (int mt = 0; mt < 2; mt++)
#pragma unroll
      for (int ks = 0; ks < 4; ks++)
        w1f[p][mt][ks] =
            *(const short8_t*)&W1F[p * 32768 + (((2 * w + mt) * 4 + ks) * 64 + l) * 8];

  // ---------------- phase 0: features, 8 threads per row ----------------
  {
    const int r = tid >> 3, sub = tid & 7;
    auto put = [&](int k, float x) {
      unsigned short hh = f2bf(x);
      unsigned short ll = f2bf(x - bf2f(hh));
      int sidx = (r * 128 + k) ^ ((r & 7) << 3);
      fea[0][sidx] = (short)hh;
      fea[1][sidx] = (short)ll;
    };
    if (sub < 6) {
      const bool isV = (sub >= 3);
      const float* Pb = isV ? Vn : Pn;
      const float* Eb = isV ? Vego : Pego;
      const int c0 = isV ? 56 : 0;
      float p0 = Pb[(b * NN + r) * 2 + 0], p1 = Pb[(b * NN + r) * 2 + 1];
      float e0 = Eb[b * 2 + 0], e1 = Eb[b * 2 + 1];
      float d0 = p0 - e0, d1 = p1 - e1;
      int s = sub - (isV ? 3 : 0);
      if (s == 0) {
        put(c0 + 0, e0); put(c0 + 1, e1); put(c0 + 2, p0); put(c0 + 3, p1);
        put(c0 + 4, d0); put(c0 + 5, d1); put(c0 + 6, d0); put(c0 + 7, d1);
        float q0 = d0 * d0 + EPS, q1 = d1 * d1 + EPS;
        float c30 = (d0 * d0) * d0 + EPS, c31 = (d1 * d1) * d1 + EPS;
        float ex0 = expf(d0) + EPS, ex1 = expf(d1) + EPS;
        put(c0 + 25, q0);  put(c0 + 26, q1);
        put(c0 + 27, c30); put(c0 + 28, c31);
        put(c0 + 29, ex0); put(c0 + 30, ex1);
        put(c0 + 31, 1.0f / (d0 + EPS)); put(c0 + 32, 1.0f / (d1 + EPS));
        put(c0 + 50, 1.0f / q0);  put(c0 + 51, 1.0f / q1);
        put(c0 + 52, 1.0f / c30); put(c0 + 53, 1.0f / c31);
        put(c0 + 54, 1.0f / ex0); put(c0 + 55, 1.0f / ex1);
        if (!isV) {
          stash[0 * 64 + r] = p0; stash[1 * 64 + r] = p1;
          stash[2 * 64 + r] = d0; stash[3 * 64 + r] = d1;
        }
      } else {
        int i0 = (s == 1) ? 0 : 9, i1 = (s == 1) ? 9 : 17;
        for (int i = i0; i < i1; i++) {
          float arg = fmaf(W_s1[i * 2 + 0], d0, fmaf(W_s1[i * 2 + 1], d1, b_s1[i]));
          float sv = sinf(arg) + EPS;
          put(c0 + 8 + i, sv);
          put(c0 + 33 + i, 1.0f / sv);
        }
      }
    } else if (sub == 6) {
      put(112, Cn[(b * NN + r) * 2 + 0]);
      put(113, Cn[(b * NN + r) * 2 + 1]);
      for (int k = 114; k < 121; k++) put(k, 0.0f);
    } else {
      for (int k = 121; k < 128; k++) put(k, 0.0f);
    }
  }
  __syncthreads();

  // ---------------- layer 1: [256 o] x [64 r], K=128 ----------------
  f32x4 acc1[2][4];
#pragma unroll
  for (int mt = 0; mt < 2; mt++)
#pragma unroll
    for (int nt = 0; nt < 4; nt++) acc1[mt][nt] = (f32x4)0.0f;

#pragma unroll
  for (int ks = 0; ks < 4; ks++) {
    short8_t bh[4], bl[4];
#pragma unroll
    for (int nt = 0; nt < 4; nt++) {
      int rr = nt * 16 + lr;
      int sidx = (rr * 128 + ks * 32 + lq * 8) ^ ((rr & 7) << 3);
      bh[nt] = *(const short8_t*)&fea[0][sidx];
      bl[nt] = *(const short8_t*)&fea[1][sidx];
    }
#pragma unroll
    for (int mt = 0; mt < 2; mt++)
#pragma unroll
      for (int nt = 0; nt < 4; nt++)
        acc1[mt][nt] = __builtin_amdgcn_mfma_f32_16x16x32_bf16(
            w1f[0][mt][ks], bh[nt], acc1[mt][nt], 0, 0, 0);
#pragma unroll
    for (int mt = 0; mt < 2; mt++)
#pragma unroll
      for (int nt = 0; nt < 4; nt++)
        acc1[mt][nt] = __builtin_amdgcn_mfma_f32_16x16x32_bf16(
            w1f[0][mt][ks], bl[nt], acc1[mt][nt], 0, 0, 0);
#pragma unroll
    for (int mt = 0; mt < 2; mt++)
#pragma unroll
      for (int nt = 0; nt < 4; nt++)
        acc1[mt][nt] = __builtin_amdgcn_mfma_f32_16x16x32_bf16(
            w1f[1][mt][ks], bh[nt], acc1[mt][nt], 0, 0, 0);
  }

  // ---- issue W2 fragment loads (hidden under L1 epilogue + barrier) ----
  short8_t w2f[2][8];
#pragma unroll
  for (int p = 0; p < 2; p++)
#pragma unroll
    for (int ks = 0; ks < 8; ks++)
      w2f[p][ks] = *(const short8_t*)&W2F[p * 32768 + ((w * 8 + ks) * 64 + l) * 8];

  // ---- L1 epilogue: bias + leaky + hi/lo split -> h1s ----
#pragma unroll
  for (int mt = 0; mt < 2; mt++) {
    f32x4 bb = *(const f32x4*)&b1[(2 * w + mt) * 16 + lq * 4];
    int o0 = (2 * w + mt) * 16 + lq * 4;
#pragma unroll
    for (int nt = 0; nt < 4; nt++) {
      int rr = nt * 16 + lr;
      short4_t hq, lo4;
#pragma unroll
      for (int i = 0; i < 4; i++) {
        float v = acc1[mt][nt][i] + bb[i];
        v = (v >= 0.f) ? v : 0.1f * v;
        unsigned short hh = f2bf(v);
        unsigned short ll = f2bf(v - bf2f(hh));
        hq[i] = (short)hh;
        lo4[i] = (short)ll;
      }
      int sidx = (rr * 256 + o0) ^ ((rr & 7) << 3);
      *(short4_t*)&h1s[0][sidx] = hq;
      *(short4_t*)&h1s[1][sidx] = lo4;
    }
  }
  __syncthreads();

  // ---------------- layer 2: [128 o] x [64 r], K=256 ----------------
  f32x4 acc2[4];
#pragma unroll
  for (int nt = 0; nt < 4; nt++) acc2[nt] = (f32x4)0.0f;

#pragma unroll
  for (int ks = 0; ks < 8; ks++) {
    short8_t bh[4], bl[4];
#pragma unroll
    for (int nt = 0; nt < 4; nt++) {
      int rr = nt * 16 + lr;
      int sidx = (rr * 256 + ks * 32 + lq * 8) ^ ((rr & 7) << 3);
      bh[nt] = *(const short8_t*)&h1s[0][sidx];
      bl[nt] = *(const short8_t*)&h1s[1][sidx];
    }
#pragma unroll
    for (int nt = 0; nt < 4; nt++)
      acc2[nt] = __builtin_amdgcn_mfma_f32_16x16x32_bf16(
          w2f[0][ks], bh[nt], acc2[nt], 0, 0, 0);
#pragma unroll
    for (int nt = 0; nt < 4; nt++)
      acc2[nt] = __builtin_amdgcn_mfma_f32_16x16x32_bf16(
          w2f[0][ks], bl[nt], acc2[nt], 0, 0, 0);
#pragma unroll
    for (int nt = 0; nt < 4; nt++)
      acc2[nt] = __builtin_amdgcn_mfma_f32_16x16x32_bf16(
          w2f[1][ks], bh[nt], acc2[nt], 0, 0, 0);
  }

  // ---- L2 epilogue: bias + leaky -> h2s fp32 ----
  {
    f32x4 bb = *(const f32x4*)&b2[w * 16 + lq * 4];
    int o0 = w * 16 + lq * 4;
#pragma unroll
    for (int nt = 0; nt < 4; nt++) {
      int rr = nt * 16 + lr;
#pragma unroll
      for (int i = 0; i < 4; i++) {
        float v = acc2[nt][i] + bb[i];
        v = (v >= 0.f) ? v : 0.1f * v;
        h2s[(o0 + i) * 64 + rr] = v;
      }
    }
  }
  __syncthreads();

  // ---------------- layer 3: 128 -> 2 (fp32) ----------------
  if (tid < 128) {
    const int c = tid >> 6, r = tid & 63;
    float a = b3[c];
#pragma unroll 8
    for (int k = 0; k < 128; k++)
      a = fmaf(h2s[k * 64 + r], W3[c * 128 + k], a);
    en_s[r * 2 + c] = a;
  }
  __syncthreads();

  // ---------------- logits + softmax over neighbors + reduce ----------------
  if (tid < 64) {
    const int r = tid;
    float E0 = en_s[r * 2 + 0], E1 = en_s[r * 2 + 1];
    float pn0 = stash[0 * 64 + r], pn1 = stash[1 * 64 + r];
    float dp0 = stash[2 * 64 + r], dp1 = stash[3 * 64 + r];
    float logit = bw[0];
    logit = fmaf(E0, Ww[0], logit);
    logit = fmaf(E1, Ww[1], logit);
    logit = fmaf(pn0, Ww[2], logit);
    logit = fmaf(pn1, Ww[3], logit);
    logit = fmaf(dp0, Ww[4], logit);
    logit = fmaf(dp1, Ww[5], logit);
    float m = logit;
#pragma unroll
    for (int off = 32; off > 0; off >>= 1) m = fmaxf(m, __shfl_xor(m, off));
    float e = expf(logit - m);
    float ssum = e;
#pragma unroll
    for (int off = 32; off > 0; off >>= 1) ssum += __shfl_xor(ssum, off);
    float wgt = e / ssum;
    float o0 = wgt * E0, o1 = wgt * E1;
#pragma unroll
    for (int off = 32; off > 0; off >>= 1) {
      o0 += __shfl_xor(o0, off);
      o1 += __shfl_xor(o1, off);
    }
    if (r == 0) {
      out[b * 4 + 2] = o0;
      out[b * 4 + 3] = o1;
    }
  }
}

// ---------------------------------------------------------------------------
extern "C" void kernel_launch(void* const* d_in, const int* in_sizes, int n_in,
                              void* d_out, int out_size, void* d_ws, size_t ws_size,
                              hipStream_t stream) {
  const float* ego_y = (const float*)d_in[0];
  const float* Pn    = (const float*)d_in[1];
  const float* Pego  = (const float*)d_in[2];
  const float* Vn    = (const float*)d_in[3];
  const float* Vego  = (const float*)d_in[4];
  const float* Cn    = (const float*)d_in[5];
  const float* W_sel = (const float*)d_in[6];
  const float* b_sel = (const float*)d_in[7];
  const float* W_s0  = (const float*)d_in[8];
  const float* b_s0  = (const float*)d_in[9];
  const float* W_map = (const float*)d_in[10];
  const float* b_map = (const float*)d_in[11];
  const float* W_efc = (const float*)d_in[12];
  const float* b_efc = (const float*)d_in[13];
  const float* W_s1  = (const float*)d_in[14];
  const float* b_s1  = (const float*)d_in[15];
  const float* W1    = (const float*)d_in[16];
  const float* b1    = (const float*)d_in[17];
  const float* W2    = (const float*)d_in[18];
  const float* b2    = (const float*)d_in[19];
  const float* W3    = (const float*)d_in[20];
  const float* b3    = (const float*)d_in[21];
  const float* Ww    = (const float*)d_in[22];
  const float* bw    = (const float*)d_in[23];
  float* out = (float*)d_out;

  short* W1F = (short*)d_ws;          // 2 planes x 32768 shorts = 128 KB
  short* W2F = W1F + 65536;           // 2 planes x 32768 shorts = 128 KB

  w_prep_kernel<<<16, 256, 0, stream>>>(W1, W2, W1F, W2F);
  er_kernel<<<NB / 256, 256, 0, stream>>>(ego_y, W_sel, b_sel, W_s0, b_s0,
                                          W_map, b_map, W_efc, b_efc, out);
  en_kernel<<<NB, 512, 0, stream>>>(Pn, Pego, Vn, Vego, Cn, W_s1, b_s1,
                                    b1, b2, W3, b3, Ww, bw, W1F, W2F, out);
}

// Round 3
// 321.673 us; speedup vs baseline: 2.2518x; 1.0360x over previous
//
#include <hip/hip_runtime.h>
#include <math.h>

#define EPS 1e-6f
#define NB 4096
#define NN 64

typedef __attribute__((ext_vector_type(8))) short short8_t;
typedef __attribute__((ext_vector_type(4))) short short4_t;
typedef __attribute__((ext_vector_type(4))) float f32x4;

__device__ __forceinline__ unsigned short f2bf(float x) {
  unsigned u = __float_as_uint(x);
  u = u + 0x7fffu + ((u >> 16) & 1u);
  return (unsigned short)(u >> 16);
}

// XOR swizzle in SHORT units: byte bits 4,7,8  -> 2-way (free) fragment reads
__device__ __forceinline__ int swz(int r) {
  return ((r & 1) << 3) | (((r >> 1) & 3) << 6);
}

// ---------------------------------------------------------------------------
// Pre-gather weights into MFMA fragment-major images (bf16 hi/lo planes).
// W1F: [p][mt 0..15][ks 0..3][lane][j]  (k>=114 zero-padded), plane stride 32768
// W2F: [p][mt 0..7 ][ks 0..7][lane][j],                        plane stride 32768
// value = W[m = mt*16 + (l&15)][k = ks*32 + (l>>4)*8 + j]
// ---------------------------------------------------------------------------
__global__ void w_prep_kernel(const float* __restrict__ W1,
                              const float* __restrict__ W2,
                              short* __restrict__ W1F,
                              short* __restrict__ W2F) {
  int t = blockIdx.x * blockDim.x + threadIdx.x;
  if (t >= 4096) return;
  {
    int l = t & 63, ks = (t >> 6) & 3, mt = t >> 8;  // mt 0..15
    int m = mt * 16 + (l & 15);
#pragma unroll
    for (int j = 0; j < 8; j++) {
      int k = ks * 32 + (l >> 4) * 8 + j;
      float x = (k < 114) ? W1[m * 114 + k] : 0.0f;
      unsigned u = __float_as_uint(x);
      unsigned short hh = (unsigned short)(u >> 16);  // trunc split
      unsigned short ll = f2bf(x - __uint_as_float(u & 0xFFFF0000u));
      int base = ((mt * 4 + ks) * 64 + l) * 8 + j;
      W1F[base] = (short)hh;
      W1F[32768 + base] = (short)ll;
    }
  }
  {
    int l = t & 63, ks = (t >> 6) & 7, mt = t >> 9;  // mt 0..7
    int m = mt * 16 + (l & 15);
#pragma unroll
    for (int j = 0; j < 8; j++) {
      int k = ks * 32 + (l >> 4) * 8 + j;
      float x = W2[m * 256 + k];
      unsigned u = __float_as_uint(x);
      unsigned short hh = (unsigned short)(u >> 16);
      unsigned short ll = f2bf(x - __uint_as_float(u & 0xFFFF0000u));
      int base = ((mt * 8 + ks) * 64 + l) * 8 + j;
      W2F[base] = (short)hh;
      W2F[32768 + base] = (short)ll;
    }
  }
}

// ---------------------------------------------------------------------------
// Er net: one thread per batch row (fp32), fully unrolled (regs, no scratch).
// ---------------------------------------------------------------------------
__global__ __launch_bounds__(64)
void er_kernel(const float* __restrict__ ego_y,
               const float* __restrict__ W_sel, const float* __restrict__ b_sel,
               const float* __restrict__ W_s0,  const float* __restrict__ b_s0,
               const float* __restrict__ W_map, const float* __restrict__ b_map,
               const float* __restrict__ W_efc, const float* __restrict__ b_efc,
               float* __restrict__ out) {
  int b = blockIdx.x * blockDim.x + threadIdx.x;
  if (b >= NB) return;
  const float lane[4] = {13.55f, 17.45f, 21.12f, 24.91f};
  float ego = ego_y[b];
  float dy[4];
#pragma unroll
  for (int j = 0; j < 4; j++) dy[j] = lane[j] - ego;

  float t[4];
#pragma unroll
  for (int i = 0; i < 4; i++) {
    float a = b_sel[i];
#pragma unroll
    for (int j = 0; j < 4; j++) a = fmaf(W_sel[i * 4 + j], dy[j], a);
    t[i] = a;
  }
  float m = fmaxf(fmaxf(t[0], t[1]), fmaxf(t[2], t[3]));
  float e[4], s = 0.f;
#pragma unroll
  for (int i = 0; i < 4; i++) { e[i] = expf(t[i] - m); s += e[i]; }
  float x[4];
#pragma unroll
  for (int i = 0; i < 4; i++) x[i] = (e[i] / s) * dy[i];

  float f[48];
  float sn[8];
#pragma unroll
  for (int k = 0; k < 8; k++) {
    float a = b_s0[k];
#pragma unroll
    for (int j = 0; j < 4; j++) a = fmaf(W_s0[k * 4 + j], x[j], a);
    sn[k] = sinf(a) + EPS;
  }
#pragma unroll
  for (int i = 0; i < 4; i++) f[i] = x[i];
#pragma unroll
  for (int k = 0; k < 8; k++) f[4 + k] = sn[k];
#pragma unroll
  for (int i = 0; i < 4; i++) {
    float q = x[i] * x[i] + EPS;
    f[12 + i] = q; f[36 + i] = 1.0f / q;
  }
#pragma unroll
  for (int i = 0; i < 4; i++) {
    float c3 = (x[i] * x[i]) * x[i] + EPS;
    f[16 + i] = c3; f[40 + i] = 1.0f / c3;
  }
#pragma unroll
  for (int i = 0; i < 4; i++) {
    float ex = expf(x[i]) + EPS;
    f[20 + i] = ex; f[44 + i] = 1.0f / ex;
  }
#pragma unroll
  for (int i = 0; i < 4; i++) f[24 + i] = 1.0f / (x[i] + EPS);
#pragma unroll
  for (int k = 0; k < 8; k++) f[28 + k] = 1.0f / sn[k];

  float y[8];
#pragma unroll
  for (int i = 0; i < 8; i++) {
    float a = b_map[i];
#pragma unroll
    for (int k = 0; k < 48; k++) a = fmaf(W_map[i * 48 + k], f[k], a);
    y[i] = fmaxf(a, 0.1f * a);
  }
#pragma unroll
  for (int c = 0; c < 2; c++) {
    float a = b_efc[c];
#pragma unroll
    for (int i = 0; i < 8; i++) a = fmaf(W_efc[c * 8 + i], y[i], a);
    out[b * 4 + c] = a;
  }
}

// ---------------------------------------------------------------------------
// En net: one block (512 thr, 8 waves) per batch. bf16 hi/lo 3-pass MFMA.
// fea: [64 r][256 c] shorts, c = (k>>3)*16 + p*8 + (k&7), c ^= swz(r)
// h1s: [64 r][512 c] shorts, c = (o>>3)*16 + p*8 + (o&7), c ^= swz(r)
// h2s: [64 r][132]   fp32 (pad 4)
// ---------------------------------------------------------------------------
__global__ __launch_bounds__(512)
void en_kernel(const float* __restrict__ Pn, const float* __restrict__ Pego,
               const float* __restrict__ Vn, const float* __restrict__ Vego,
               const float* __restrict__ Cn,
               const float* __restrict__ W_s1, const float* __restrict__ b_s1,
               const float* __restrict__ b1, const float* __restrict__ b2,
               const float* __restrict__ W3, const float* __restrict__ b3,
               const float* __restrict__ Ww, const float* __restrict__ bw,
               const short* __restrict__ W1F, const short* __restrict__ W2F,
               float* __restrict__ out) {
  __shared__ __align__(16) short fea[64 * 256];
  __shared__ __align__(16) short h1s[64 * 512];
  __shared__ __align__(16) float h2s[64 * 132];
  __shared__ float stash[4 * 64];
  __shared__ float en_s[NN * 2];

  const int b = blockIdx.x;
  const int tid = threadIdx.x;
  const int w = tid >> 6;   // wave 0..7
  const int l = tid & 63;
  const int lr = l & 15;    // fragment row/col index
  const int lq = l >> 4;    // k-quad

  // ---- issue W1 fragment loads early (hidden under feature build) ----
  short8_t w1f[2][2][4];  // [plane][mt][ks]
#pragma unroll
  for (int p = 0; p < 2; p++)
#pragma unroll
    for (int mt = 0; mt < 2; mt++)
#pragma unroll
      for (int ks = 0; ks < 4; ks++)
        w1f[p][mt][ks] =
            *(const short8_t*)&W1F[p * 32768 + (((2 * w + mt) * 4 + ks) * 64 + l) * 8];

  // ---------------- phase 0: features, 8 threads per row ----------------
  {
    const int r = tid >> 3, sub = tid & 7;
    const int rbase = r * 256, rsw = swz(r);
    auto put = [&](int k, float x) {
      unsigned u = __float_as_uint(x);
      unsigned short hh = (unsigned short)(u >> 16);  // trunc split
      unsigned short ll = f2bf(x - __uint_as_float(u & 0xFFFF0000u));
      int c = ((k >> 3) << 4) + (k & 7);
      fea[rbase + (c ^ rsw)] = (short)hh;
      fea[rbase + ((c + 8) ^ rsw)] = (short)ll;
    };
    if (sub < 6) {
      const bool isV = (sub >= 3);
      const float* Pb = isV ? Vn : Pn;
      const float* Eb = isV ? Vego : Pego;
      const int c0 = isV ? 56 : 0;
      float p0 = Pb[(b * NN + r) * 2 + 0], p1 = Pb[(b * NN + r) * 2 + 1];
      float e0 = Eb[b * 2 + 0], e1 = Eb[b * 2 + 1];
      float d0 = p0 - e0, d1 = p1 - e1;
      int s = sub - (isV ? 3 : 0);
      if (s == 0) {
        put(c0 + 0, e0); put(c0 + 1, e1); put(c0 + 2, p0); put(c0 + 3, p1);
        put(c0 + 4, d0); put(c0 + 5, d1); put(c0 + 6, d0); put(c0 + 7, d1);
        float q0 = d0 * d0 + EPS, q1 = d1 * d1 + EPS;
        float c30 = (d0 * d0) * d0 + EPS, c31 = (d1 * d1) * d1 + EPS;
        float ex0 = expf(d0) + EPS, ex1 = expf(d1) + EPS;
        put(c0 + 25, q0);  put(c0 + 26, q1);
        put(c0 + 27, c30); put(c0 + 28, c31);
        put(c0 + 29, ex0); put(c0 + 30, ex1);
        put(c0 + 31, 1.0f / (d0 + EPS)); put(c0 + 32, 1.0f / (d1 + EPS));
        put(c0 + 50, 1.0f / q0);  put(c0 + 51, 1.0f / q1);
        put(c0 + 52, 1.0f / c30); put(c0 + 53, 1.0f / c31);
        put(c0 + 54, 1.0f / ex0); put(c0 + 55, 1.0f / ex1);
        if (!isV) {
          stash[0 * 64 + r] = p0; stash[1 * 64 + r] = p1;
          stash[2 * 64 + r] = d0; stash[3 * 64 + r] = d1;
        }
      } else {
        int i0 = (s == 1) ? 0 : 9, i1 = (s == 1) ? 9 : 17;
        for (int i = i0; i < i1; i++) {
          float arg = fmaf(W_s1[i * 2 + 0], d0, fmaf(W_s1[i * 2 + 1], d1, b_s1[i]));
          float sv = sinf(arg) + EPS;
          put(c0 + 8 + i, sv);
          put(c0 + 33 + i, 1.0f / sv);
        }
      }
    } else if (sub == 6) {
      put(112, Cn[(b * NN + r) * 2 + 0]);
      put(113, Cn[(b * NN + r) * 2 + 1]);
      for (int k = 114; k < 121; k++) put(k, 0.0f);
    } else {
      for (int k = 121; k < 128; k++) put(k, 0.0f);
    }
  }
  __syncthreads();

  // ---------------- layer 1: [256 o] x [64 r], K=128 ----------------
  f32x4 acc1[2][4];
#pragma unroll
  for (int mt = 0; mt < 2; mt++)
#pragma unroll
    for (int nt = 0; nt < 4; nt++) acc1[mt][nt] = (f32x4)0.0f;

#pragma unroll
  for (int ks = 0; ks < 4; ks++) {
    short8_t bh[4], bl[4];
#pragma unroll
    for (int nt = 0; nt < 4; nt++) {
      int rr = nt * 16 + lr;
      int c0 = (ks * 4 + lq) << 4;
      int sw = swz(rr);
      bh[nt] = *(const short8_t*)&fea[rr * 256 + (c0 ^ sw)];
      bl[nt] = *(const short8_t*)&fea[rr * 256 + ((c0 + 8) ^ sw)];
    }
#pragma unroll
    for (int mt = 0; mt < 2; mt++)
#pragma unroll
      for (int nt = 0; nt < 4; nt++)
        acc1[mt][nt] = __builtin_amdgcn_mfma_f32_16x16x32_bf16(
            w1f[0][mt][ks], bh[nt], acc1[mt][nt], 0, 0, 0);
#pragma unroll
    for (int mt = 0; mt < 2; mt++)
#pragma unroll
      for (int nt = 0; nt < 4; nt++)
        acc1[mt][nt] = __builtin_amdgcn_mfma_f32_16x16x32_bf16(
            w1f[0][mt][ks], bl[nt], acc1[mt][nt], 0, 0, 0);
#pragma unroll
    for (int mt = 0; mt < 2; mt++)
#pragma unroll
      for (int nt = 0; nt < 4; nt++)
        acc1[mt][nt] = __builtin_amdgcn_mfma_f32_16x16x32_bf16(
            w1f[1][mt][ks], bh[nt], acc1[mt][nt], 0, 0, 0);
  }

  // ---- issue W2 fragment loads (hidden under L1 epilogue + barrier) ----
  short8_t w2f[2][8];
#pragma unroll
  for (int p = 0; p < 2; p++)
#pragma unroll
    for (int ks = 0; ks < 8; ks++)
      w2f[p][ks] = *(const short8_t*)&W2F[p * 32768 + ((w * 8 + ks) * 64 + l) * 8];

  // ---- L1 epilogue: bias + leaky + trunc hi/lo split -> h1s ----
#pragma unroll
  for (int mt = 0; mt < 2; mt++) {
    f32x4 bb = *(const f32x4*)&b1[(2 * w + mt) * 16 + lq * 4];
    int g = (2 * w + mt) * 2 + (lq >> 1);
    int colh = g * 16 + (lq & 1) * 4;
#pragma unroll
    for (int nt = 0; nt < 4; nt++) {
      int rr = nt * 16 + lr;
      short4_t hq, lo4;
#pragma unroll
      for (int i = 0; i < 4; i++) {
        float v = acc1[mt][nt][i] + bb[i];
        v = fmaxf(v, 0.1f * v);
        unsigned u = __float_as_uint(v);
        hq[i] = (short)(unsigned short)(u >> 16);
        lo4[i] = (short)f2bf(v - __uint_as_float(u & 0xFFFF0000u));
      }
      int sw = swz(rr);
      *(short4_t*)&h1s[rr * 512 + (colh ^ sw)] = hq;
      *(short4_t*)&h1s[rr * 512 + ((colh + 8) ^ sw)] = lo4;
    }
  }
  __syncthreads();

  // ---------------- layer 2: [128 o] x [64 r], K=256 ----------------
  f32x4 acc2[4];
#pragma unroll
  for (int nt = 0; nt < 4; nt++) acc2[nt] = (f32x4)0.0f;

#pragma unroll
  for (int ks = 0; ks < 8; ks++) {
    short8_t bh[4], bl[4];
#pragma unroll
    for (int nt = 0; nt < 4; nt++) {
      int rr = nt * 16 + lr;
      int c0 = (ks * 4 + lq) << 4;
      int sw = swz(rr);
      bh[nt] = *(const short8_t*)&h1s[rr * 512 + (c0 ^ sw)];
      bl[nt] = *(const short8_t*)&h1s[rr * 512 + ((c0 + 8) ^ sw)];
    }
#pragma unroll
    for (int nt = 0; nt < 4; nt++)
      acc2[nt] = __builtin_amdgcn_mfma_f32_16x16x32_bf16(
          w2f[0][ks], bh[nt], acc2[nt], 0, 0, 0);
#pragma unroll
    for (int nt = 0; nt < 4; nt++)
      acc2[nt] = __builtin_amdgcn_mfma_f32_16x16x32_bf16(
          w2f[0][ks], bl[nt], acc2[nt], 0, 0, 0);
#pragma unroll
    for (int nt = 0; nt < 4; nt++)
      acc2[nt] = __builtin_amdgcn_mfma_f32_16x16x32_bf16(
          w2f[1][ks], bh[nt], acc2[nt], 0, 0, 0);
  }

  // ---- L2 epilogue: bias + leaky -> h2s fp32 [r][o] ----
  {
    f32x4 bb = *(const f32x4*)&b2[w * 16 + lq * 4];
    int o0 = w * 16 + lq * 4;
#pragma unroll
    for (int nt = 0; nt < 4; nt++) {
      int rr = nt * 16 + lr;
      f32x4 v;
#pragma unroll
      for (int i = 0; i < 4; i++) {
        float u = acc2[nt][i] + bb[i];
        v[i] = fmaxf(u, 0.1f * u);
      }
      *(f32x4*)&h2s[rr * 132 + o0] = v;
    }
  }
  __syncthreads();

  // ---------------- layer 3: 128 -> 2 (fp32, vectorized rows) ----------------
  if (tid < 128) {
    const int c = tid >> 6, r = tid & 63;
    float a0 = b3[c], a1 = 0.f, a2 = 0.f, a3 = 0.f;
#pragma unroll 8
    for (int k = 0; k < 128; k += 4) {
      f32x4 h = *(const f32x4*)&h2s[r * 132 + k];
      a0 = fmaf(h[0], W3[c * 128 + k + 0], a0);
      a1 = fmaf(h[1], W3[c * 128 + k + 1], a1);
      a2 = fmaf(h[2], W3[c * 128 + k + 2], a2);
      a3 = fmaf(h[3], W3[c * 128 + k + 3], a3);
    }
    en_s[r * 2 + c] = ((a0 + a1) + (a2 + a3));
  }
  __syncthreads();

  // ---------------- logits + softmax over neighbors + reduce ----------------
  if (tid < 64) {
    const int r = tid;
    float E0 = en_s[r * 2 + 0], E1 = en_s[r * 2 + 1];
    float pn0 = stash[0 * 64 + r], pn1 = stash[1 * 64 + r];
    float dp0 = stash[2 * 64 + r], dp1 = stash[3 * 64 + r];
    float logit = bw[0];
    logit = fmaf(E0, Ww[0], logit);
    logit = fmaf(E1, Ww[1], logit);
    logit = fmaf(pn0, Ww[2], logit);
    logit = fmaf(pn1, Ww[3], logit);
    logit = fmaf(dp0, Ww[4], logit);
    logit = fmaf(dp1, Ww[5], logit);
    float m = logit;
#pragma unroll
    for (int off = 32; off > 0; off >>= 1) m = fmaxf(m, __shfl_xor(m, off));
    float e = expf(logit - m);
    float ssum = e;
#pragma unroll
    for (int off = 32; off > 0; off >>= 1) ssum += __shfl_xor(ssum, off);
    float wgt = e / ssum;
    float o0 = wgt * E0, o1 = wgt * E1;
#pragma unroll
    for (int off = 32; off > 0; off >>= 1) {
      o0 += __shfl_xor(o0, off);
      o1 += __shfl_xor(o1, off);
    }
    if (r == 0) {
      out[b * 4 + 2] = o0;
      out[b * 4 + 3] = o1;
    }
  }
}

// ---------------------------------------------------------------------------
extern "C" void kernel_launch(void* const* d_in, const int* in_sizes, int n_in,
                              void* d_out, int out_size, void* d_ws, size_t ws_size,
                              hipStream_t stream) {
  const float* ego_y = (const float*)d_in[0];
  const float* Pn    = (const float*)d_in[1];
  const float* Pego  = (const float*)d_in[2];
  const float* Vn    = (const float*)d_in[3];
  const float* Vego  = (const float*)d_in[4];
  const float* Cn    = (const float*)d_in[5];
  const float* W_sel = (const float*)d_in[6];
  const float* b_sel = (const float*)d_in[7];
  const float* W_s0  = (const float*)d_in[8];
  const float* b_s0  = (const float*)d_in[9];
  const float* W_map = (const float*)d_in[10];
  const float* b_map = (const float*)d_in[11];
  const float* W_efc = (const float*)d_in[12];
  const float* b_efc = (const float*)d_in[13];
  const float* W_s1  = (const float*)d_in[14];
  const float* b_s1  = (const float*)d_in[15];
  const float* W1    = (const float*)d_in[16];
  const float* b1    = (const float*)d_in[17];
  const float* W2    = (const float*)d_in[18];
  const float* b2    = (const float*)d_in[19];
  const float* W3    = (const float*)d_in[20];
  const float* b3    = (const float*)d_in[21];
  const float* Ww    = (const float*)d_in[22];
  const float* bw    = (const float*)d_in[23];
  float* out = (float*)d_out;

  short* W1F = (short*)d_ws;          // 2 planes x 32768 shorts = 128 KB
  short* W2F = W1F + 65536;           // 2 planes x 32768 shorts = 128 KB

  w_prep_kernel<<<16, 256, 0, stream>>>(W1, W2, W1F, W2F);
  en_kernel<<<NB, 512, 0, stream>>>(Pn, Pego, Vn, Vego, Cn, W_s1, b_s1,
                                    b1, b2, W3, b3, Ww, bw, W1F, W2F, out);
  er_kernel<<<NB / 64, 64, 0, stream>>>(ego_y, W_sel, b_sel, W_s0, b_s0,
                                        W_map, b_map, W_efc, b_efc, out);
}

// Round 4
// 293.385 us; speedup vs baseline: 2.4689x; 1.0964x over previous
//
#include <hip/hip_runtime.h>
#include <math.h>

#define EPS 1e-6f
#define NB 4096
#define NN 64

typedef __attribute__((ext_vector_type(8))) short short8_t;
typedef __attribute__((ext_vector_type(4))) short short4_t;
typedef __attribute__((ext_vector_type(4))) float f32x4;

__device__ __forceinline__ unsigned short f2bf(float x) {
  unsigned u = __float_as_uint(x);
  u = u + 0x7fffu + ((u >> 16) & 1u);
  return (unsigned short)(u >> 16);
}

// ---------------------------------------------------------------------------
// Pre-gather weights into MFMA fragment-major images (bf16 hi/lo planes).
// W1F: [p][MT 0..15][ks 0..3][lane][j]  (k>=114 zero-padded), plane stride 32768
// W2F: [p][MT 0..7 ][ks 0..7][lane][j],                        plane stride 32768
// value = W[m = MT*16 + (l&15)][k = ks*32 + (l>>4)*8 + j]
// ---------------------------------------------------------------------------
__global__ void w_prep_kernel(const float* __restrict__ W1,
                              const float* __restrict__ W2,
                              short* __restrict__ W1F,
                              short* __restrict__ W2F) {
  int t = blockIdx.x * blockDim.x + threadIdx.x;
  if (t >= 4096) return;
  {
    int l = t & 63, ks = (t >> 6) & 3, mt = t >> 8;  // mt 0..15
    int m = mt * 16 + (l & 15);
#pragma unroll
    for (int j = 0; j < 8; j++) {
      int k = ks * 32 + (l >> 4) * 8 + j;
      float x = (k < 114) ? W1[m * 114 + k] : 0.0f;
      unsigned u = __float_as_uint(x);
      unsigned short hh = (unsigned short)(u >> 16);  // trunc split
      unsigned short ll = f2bf(x - __uint_as_float(u & 0xFFFF0000u));
      int base = ((mt * 4 + ks) * 64 + l) * 8 + j;
      W1F[base] = (short)hh;
      W1F[32768 + base] = (short)ll;
    }
  }
  {
    int l = t & 63, ks = (t >> 6) & 7, mt = t >> 9;  // mt 0..7
    int m = mt * 16 + (l & 15);
#pragma unroll
    for (int j = 0; j < 8; j++) {
      int k = ks * 32 + (l >> 4) * 8 + j;
      float x = W2[m * 256 + k];
      unsigned u = __float_as_uint(x);
      unsigned short hh = (unsigned short)(u >> 16);
      unsigned short ll = f2bf(x - __uint_as_float(u & 0xFFFF0000u));
      int base = ((mt * 8 + ks) * 64 + l) * 8 + j;
      W2F[base] = (short)hh;
      W2F[32768 + base] = (short)ll;
    }
  }
}

// ---------------------------------------------------------------------------
// Er net: 8 threads per batch row, 32 batches per 256-thread block.
// Weights staged in LDS; y-reduction via 8-lane shuffle group.
// ---------------------------------------------------------------------------
__global__ __launch_bounds__(256)
void er_kernel(const float* __restrict__ ego_y,
               const float* __restrict__ W_sel, const float* __restrict__ b_sel,
               const float* __restrict__ W_s0,  const float* __restrict__ b_s0,
               const float* __restrict__ W_map, const float* __restrict__ b_map,
               const float* __restrict__ W_efc, const float* __restrict__ b_efc,
               float* __restrict__ out) {
  __shared__ float sm[470];
  const int tid = threadIdx.x;
  for (int i = tid; i < 470; i += 256) {
    float v;
    if (i < 384) v = W_map[i];
    else if (i < 392) v = b_map[i - 384];
    else if (i < 408) v = W_sel[i - 392];
    else if (i < 412) v = b_sel[i - 408];
    else if (i < 444) v = W_s0[i - 412];
    else if (i < 452) v = b_s0[i - 444];
    else if (i < 468) v = W_efc[i - 452];
    else v = b_efc[i - 468];
    sm[i] = v;
  }
  __syncthreads();
  const float* sWmap = sm;
  const float* sbmap = sm + 384;
  const float* sWsel = sm + 392;
  const float* sbsel = sm + 408;
  const float* sWs0  = sm + 412;
  const float* sbs0  = sm + 444;
  const float* sWefc = sm + 452;
  const float* sbefc = sm + 468;

  const int b = blockIdx.x * 32 + (tid >> 3);
  const int sub = tid & 7;
  const float lane[4] = {13.55f, 17.45f, 21.12f, 24.91f};
  float ego = ego_y[b];
  float dy[4];
#pragma unroll
  for (int j = 0; j < 4; j++) dy[j] = lane[j] - ego;

  float t[4];
#pragma unroll
  for (int i = 0; i < 4; i++) {
    float a = sbsel[i];
#pragma unroll
    for (int j = 0; j < 4; j++) a = fmaf(sWsel[i * 4 + j], dy[j], a);
    t[i] = a;
  }
  float m = fmaxf(fmaxf(t[0], t[1]), fmaxf(t[2], t[3]));
  float e[4], s = 0.f;
#pragma unroll
  for (int i = 0; i < 4; i++) { e[i] = expf(t[i] - m); s += e[i]; }
  float x[4];
#pragma unroll
  for (int i = 0; i < 4; i++) x[i] = (e[i] / s) * dy[i];

  float f[48];
  float sn[8];
#pragma unroll
  for (int k = 0; k < 8; k++) {
    float a = sbs0[k];
#pragma unroll
    for (int j = 0; j < 4; j++) a = fmaf(sWs0[k * 4 + j], x[j], a);
    sn[k] = sinf(a) + EPS;
  }
#pragma unroll
  for (int i = 0; i < 4; i++) f[i] = x[i];
#pragma unroll
  for (int k = 0; k < 8; k++) f[4 + k] = sn[k];
#pragma unroll
  for (int i = 0; i < 4; i++) {
    float q = x[i] * x[i] + EPS;
    f[12 + i] = q; f[36 + i] = 1.0f / q;
  }
#pragma unroll
  for (int i = 0; i < 4; i++) {
    float c3 = (x[i] * x[i]) * x[i] + EPS;
    f[16 + i] = c3; f[40 + i] = 1.0f / c3;
  }
#pragma unroll
  for (int i = 0; i < 4; i++) {
    float ex = expf(x[i]) + EPS;
    f[20 + i] = ex; f[44 + i] = 1.0f / ex;
  }
#pragma unroll
  for (int i = 0; i < 4; i++) f[24 + i] = 1.0f / (x[i] + EPS);
#pragma unroll
  for (int k = 0; k < 8; k++) f[28 + k] = 1.0f / sn[k];

  // y[sub] = leaky(W_map[sub] . f + b_map[sub])
  float a = sbmap[sub];
#pragma unroll
  for (int k = 0; k < 48; k++) a = fmaf(sWmap[sub * 48 + k], f[k], a);
  float y = fmaxf(a, 0.1f * a);

  float t0 = sWefc[0 * 8 + sub] * y;
  float t1 = sWefc[1 * 8 + sub] * y;
#pragma unroll
  for (int off = 4; off > 0; off >>= 1) {
    t0 += __shfl_xor(t0, off);
    t1 += __shfl_xor(t1, off);
  }
  if (sub == 0) {
    out[b * 4 + 0] = t0 + sbefc[0];
    out[b * 4 + 1] = t1 + sbefc[1];
  }
}

// ---------------------------------------------------------------------------
// En net: one block (512 thr, 8 waves) per batch. bf16 hi/lo 3-pass MFMA.
// fea: [p][64 r][128 k] shorts, idx = r*128 + (k ^ ((r&7)<<3))   (bank bits 4-6)
// h1s: [p][64 r][256 o] shorts, idx = r*256 + (o ^ ((r&7)<<3))
// h2s: [64 r][132 o]   fp32 (pad 4 -> natural swizzle)
// Wave tiling: L1 4m x 2n, L2 2m x 2n  (halves redundant B-fragment reads)
// ---------------------------------------------------------------------------
__global__ __launch_bounds__(512, 2)
void en_kernel(const float* __restrict__ Pn, const float* __restrict__ Pego,
               const float* __restrict__ Vn, const float* __restrict__ Vego,
               const float* __restrict__ Cn,
               const float* __restrict__ W_s1, const float* __restrict__ b_s1,
               const float* __restrict__ b1, const float* __restrict__ b2,
               const float* __restrict__ W3, const float* __restrict__ b3,
               const float* __restrict__ Ww, const float* __restrict__ bw,
               const short* __restrict__ W1F, const short* __restrict__ W2F,
               float* __restrict__ out) {
  __shared__ __align__(16) short fea[2][64 * 128];
  __shared__ __align__(16) short h1s[2][64 * 256];
  __shared__ __align__(16) float h2s[64 * 132];
  __shared__ float stash[4 * 64];
  __shared__ float en_s[NN * 2];

  const int b = blockIdx.x;
  const int tid = threadIdx.x;
  const int w = tid >> 6;   // wave 0..7
  const int l = tid & 63;
  const int lr = l & 15;    // fragment row/col index
  const int lq = l >> 4;    // k-quad
  const int ntb = (w >> 2) * 2;  // this wave's row-tile base (2 tiles)

  // ---- issue W1 fragment loads early (hidden under feature build) ----
  // MT = (w&3)*4 + m, m = 0..3
  short8_t w1f[2][4][4];  // [plane][m][ks]
#pragma unroll
  for (int p = 0; p < 2; p++)
#pragma unroll
    for (int m = 0; m < 4; m++)
#pragma unroll
      for (int ks = 0; ks < 4; ks++)
        w1f[p][m][ks] = *(const short8_t*)
            &W1F[p * 32768 + ((((w & 3) * 4 + m) * 4 + ks) * 64 + l) * 8];

  // ---------------- phase 0: features, wave-specialized, lane = row ----------
  {
    const int r = l;
    const int rsw = (r & 7) << 3;
    auto put = [&](int k, float x) {
      unsigned u = __float_as_uint(x);
      unsigned short hh = (unsigned short)(u >> 16);  // trunc split
      unsigned short ll = f2bf(x - __uint_as_float(u & 0xFFFF0000u));
      int idx = r * 128 + (k ^ rsw);
      fea[0][idx] = (short)hh;
      fea[1][idx] = (short)ll;
    };
    if (w == 0 || w == 3) {
      // base features for P (w0) / V (w3)
      const bool isV = (w == 3);
      const float2 p2 = ((const float2*)(isV ? Vn : Pn))[b * NN + r];
      const float* Eb = isV ? Vego : Pego;
      float e0 = Eb[b * 2 + 0], e1 = Eb[b * 2 + 1];
      float d0 = p2.x - e0, d1 = p2.y - e1;
      const int c0 = isV ? 56 : 0;
      put(c0 + 0, e0); put(c0 + 1, e1); put(c0 + 2, p2.x); put(c0 + 3, p2.y);
      put(c0 + 4, d0); put(c0 + 5, d1); put(c0 + 6, d0); put(c0 + 7, d1);
      float q0 = d0 * d0 + EPS, q1 = d1 * d1 + EPS;
      float c30 = (d0 * d0) * d0 + EPS, c31 = (d1 * d1) * d1 + EPS;
      float ex0 = expf(d0) + EPS, ex1 = expf(d1) + EPS;
      put(c0 + 25, q0);  put(c0 + 26, q1);
      put(c0 + 27, c30); put(c0 + 28, c31);
      put(c0 + 29, ex0); put(c0 + 30, ex1);
      put(c0 + 31, 1.0f / (d0 + EPS)); put(c0 + 32, 1.0f / (d1 + EPS));
      put(c0 + 50, 1.0f / q0);  put(c0 + 51, 1.0f / q1);
      put(c0 + 52, 1.0f / c30); put(c0 + 53, 1.0f / c31);
      put(c0 + 54, 1.0f / ex0); put(c0 + 55, 1.0f / ex1);
      if (!isV) {
        stash[0 * 64 + r] = p2.x; stash[1 * 64 + r] = p2.y;
        stash[2 * 64 + r] = d0;   stash[3 * 64 + r] = d1;
      }
    } else if (w == 6) {
      // V sins 12..16 + Cn + zero pad
      const float2 p2 = ((const float2*)Vn)[b * NN + r];
      float e0 = Vego[b * 2 + 0], e1 = Vego[b * 2 + 1];
      float d0 = p2.x - e0, d1 = p2.y - e1;
      for (int i = 12; i < 17; i++) {
        float arg = fmaf(W_s1[i * 2 + 0], d0, fmaf(W_s1[i * 2 + 1], d1, b_s1[i]));
        float sv = sinf(arg) + EPS;
        put(56 + 8 + i, sv);
        put(56 + 33 + i, 1.0f / sv);
      }
      const float2 cn = ((const float2*)Cn)[b * NN + r];
      unsigned u0 = __float_as_uint(cn.x), u1 = __float_as_uint(cn.y);
      short8_t ghi = {0, 0, 0, 0, 0, 0, 0, 0};
      short8_t glo = {0, 0, 0, 0, 0, 0, 0, 0};
      ghi[0] = (short)(unsigned short)(u0 >> 16);
      ghi[1] = (short)(unsigned short)(u1 >> 16);
      glo[0] = (short)f2bf(cn.x - __uint_as_float(u0 & 0xFFFF0000u));
      glo[1] = (short)f2bf(cn.y - __uint_as_float(u1 & 0xFFFF0000u));
      int gi = r * 128 + (112 ^ rsw);
      *(short8_t*)&fea[0][gi] = ghi;
      *(short8_t*)&fea[1][gi] = glo;
      short8_t zz = {0, 0, 0, 0, 0, 0, 0, 0};
      int gi2 = r * 128 + (120 ^ rsw);
      *(short8_t*)&fea[0][gi2] = zz;
      *(short8_t*)&fea[1][gi2] = zz;
    } else {
      // sin slices: w1: P[0,6) w2: P[6,12) w4: P[12,17) w5: V[0,6) w7: V[6,12)
      const bool isV = (w >= 5);
      int i0, i1;
      if (w == 1 || w == 5) { i0 = 0; i1 = 6; }
      else if (w == 2 || w == 7) { i0 = 6; i1 = 12; }
      else { i0 = 12; i1 = 17; }
      const float2 p2 = ((const float2*)(isV ? Vn : Pn))[b * NN + r];
      const float* Eb = isV ? Vego : Pego;
      float e0 = Eb[b * 2 + 0], e1 = Eb[b * 2 + 1];
      float d0 = p2.x - e0, d1 = p2.y - e1;
      const int c0 = isV ? 56 : 0;
      for (int i = i0; i < i1; i++) {
        float arg = fmaf(W_s1[i * 2 + 0], d0, fmaf(W_s1[i * 2 + 1], d1, b_s1[i]));
        float sv = sinf(arg) + EPS;
        put(c0 + 8 + i, sv);
        put(c0 + 33 + i, 1.0f / sv);
      }
    }
  }
  __syncthreads();

  // ---------------- layer 1: [256 o] x [64 r], K=128 (4m x 2n) ----------------
  f32x4 acc1[4][2];
#pragma unroll
  for (int m = 0; m < 4; m++)
#pragma unroll
    for (int n = 0; n < 2; n++) acc1[m][n] = (f32x4)0.0f;

#pragma unroll
  for (int ks = 0; ks < 4; ks++) {
    short8_t bh[2], bl[2];
#pragma unroll
    for (int n = 0; n < 2; n++) {
      int rr = (ntb + n) * 16 + lr;
      int idx = rr * 128 + ((ks * 32 + lq * 8) ^ ((rr & 7) << 3));
      bh[n] = *(const short8_t*)&fea[0][idx];
      bl[n] = *(const short8_t*)&fea[1][idx];
    }
    __builtin_amdgcn_s_setprio(1);
#pragma unroll
    for (int m = 0; m < 4; m++)
#pragma unroll
      for (int n = 0; n < 2; n++)
        acc1[m][n] = __builtin_amdgcn_mfma_f32_16x16x32_bf16(
            w1f[0][m][ks], bh[n], acc1[m][n], 0, 0, 0);
#pragma unroll
    for (int m = 0; m < 4; m++)
#pragma unroll
      for (int n = 0; n < 2; n++)
        acc1[m][n] = __builtin_amdgcn_mfma_f32_16x16x32_bf16(
            w1f[0][m][ks], bl[n], acc1[m][n], 0, 0, 0);
#pragma unroll
    for (int m = 0; m < 4; m++)
#pragma unroll
      for (int n = 0; n < 2; n++)
        acc1[m][n] = __builtin_amdgcn_mfma_f32_16x16x32_bf16(
            w1f[1][m][ks], bh[n], acc1[m][n], 0, 0, 0);
    __builtin_amdgcn_s_setprio(0);
  }

  // ---- issue W2 fragment loads (w1f dead; hidden under L1 epilogue) ----
  // MT2 = (w&3)*2 + m, m = 0..1
  short8_t w2f[2][2][8];  // [plane][m][ks]
#pragma unroll
  for (int p = 0; p < 2; p++)
#pragma unroll
    for (int m = 0; m < 2; m++)
#pragma unroll
      for (int ks = 0; ks < 8; ks++)
        w2f[p][m][ks] = *(const short8_t*)
            &W2F[p * 32768 + ((((w & 3) * 2 + m) * 8 + ks) * 64 + l) * 8];

  // ---- L1 epilogue: bias + leaky + trunc hi/lo split -> h1s ----
#pragma unroll
  for (int m = 0; m < 4; m++) {
    int o0 = ((w & 3) * 4 + m) * 16 + lq * 4;
    f32x4 bb = *(const f32x4*)&b1[o0];
#pragma unroll
    for (int n = 0; n < 2; n++) {
      int rr = (ntb + n) * 16 + lr;
      short4_t hq, lo4;
#pragma unroll
      for (int i = 0; i < 4; i++) {
        float v = acc1[m][n][i] + bb[i];
        v = fmaxf(v, 0.1f * v);
        unsigned u = __float_as_uint(v);
        hq[i] = (short)(unsigned short)(u >> 16);
        lo4[i] = (short)f2bf(v - __uint_as_float(u & 0xFFFF0000u));
      }
      int idx = rr * 256 + (o0 ^ ((rr & 7) << 3));
      *(short4_t*)&h1s[0][idx] = hq;
      *(short4_t*)&h1s[1][idx] = lo4;
    }
  }
  __syncthreads();

  // ---------------- layer 2: [128 o] x [64 r], K=256 (2m x 2n) ----------------
  f32x4 acc2[2][2];
#pragma unroll
  for (int m = 0; m < 2; m++)
#pragma unroll
    for (int n = 0; n < 2; n++) acc2[m][n] = (f32x4)0.0f;

#pragma unroll
  for (int ks = 0; ks < 8; ks++) {
    short8_t bh[2], bl[2];
#pragma unroll
    for (int n = 0; n < 2; n++) {
      int rr = (ntb + n) * 16 + lr;
      int idx = rr * 256 + ((ks * 32 + lq * 8) ^ ((rr & 7) << 3));
      bh[n] = *(const short8_t*)&h1s[0][idx];
      bl[n] = *(const short8_t*)&h1s[1][idx];
    }
    __builtin_amdgcn_s_setprio(1);
#pragma unroll
    for (int m = 0; m < 2; m++)
#pragma unroll
      for (int n = 0; n < 2; n++)
        acc2[m][n] = __builtin_amdgcn_mfma_f32_16x16x32_bf16(
            w2f[0][m][ks], bh[n], acc2[m][n], 0, 0, 0);
#pragma unroll
    for (int m = 0; m < 2; m++)
#pragma unroll
      for (int n = 0; n < 2; n++)
        acc2[m][n] = __builtin_amdgcn_mfma_f32_16x16x32_bf16(
            w2f[0][m][ks], bl[n], acc2[m][n], 0, 0, 0);
#pragma unroll
    for (int m = 0; m < 2; m++)
#pragma unroll
      for (int n = 0; n < 2; n++)
        acc2[m][n] = __builtin_amdgcn_mfma_f32_16x16x32_bf16(
            w2f[1][m][ks], bh[n], acc2[m][n], 0, 0, 0);
    __builtin_amdgcn_s_setprio(0);
  }

  // ---- L2 epilogue: bias + leaky -> h2s fp32 [r][o] ----
#pragma unroll
  for (int m = 0; m < 2; m++) {
    int o0 = ((w & 3) * 2 + m) * 16 + lq * 4;
    f32x4 bb = *(const f32x4*)&b2[o0];
#pragma unroll
    for (int n = 0; n < 2; n++) {
      int rr = (ntb + n) * 16 + lr;
      f32x4 v;
#pragma unroll
      for (int i = 0; i < 4; i++) {
        float u = acc2[m][n][i] + bb[i];
        v[i] = fmaxf(u, 0.1f * u);
      }
      *(f32x4*)&h2s[rr * 132 + o0] = v;
    }
  }
  __syncthreads();

  // ---------------- layer 3: 128 -> 2 (fp32, vectorized rows) ----------------
  if (tid < 128) {
    const int c = tid >> 6, r = tid & 63;
    float a0 = b3[c], a1 = 0.f, a2 = 0.f, a3 = 0.f;
#pragma unroll 8
    for (int k = 0; k < 128; k += 4) {
      f32x4 h = *(const f32x4*)&h2s[r * 132 + k];
      a0 = fmaf(h[0], W3[c * 128 + k + 0], a0);
      a1 = fmaf(h[1], W3[c * 128 + k + 1], a1);
      a2 = fmaf(h[2], W3[c * 128 + k + 2], a2);
      a3 = fmaf(h[3], W3[c * 128 + k + 3], a3);
    }
    en_s[r * 2 + c] = ((a0 + a1) + (a2 + a3));
  }
  __syncthreads();

  // ---------------- logits + softmax over neighbors + reduce ----------------
  if (tid < 64) {
    const int r = tid;
    float E0 = en_s[r * 2 + 0], E1 = en_s[r * 2 + 1];
    float pn0 = stash[0 * 64 + r], pn1 = stash[1 * 64 + r];
    float dp0 = stash[2 * 64 + r], dp1 = stash[3 * 64 + r];
    float logit = bw[0];
    logit = fmaf(E0, Ww[0], logit);
    logit = fmaf(E1, Ww[1], logit);
    logit = fmaf(pn0, Ww[2], logit);
    logit = fmaf(pn1, Ww[3], logit);
    logit = fmaf(dp0, Ww[4], logit);
    logit = fmaf(dp1, Ww[5], logit);
    float m = logit;
#pragma unroll
    for (int off = 32; off > 0; off >>= 1) m = fmaxf(m, __shfl_xor(m, off));
    float e = expf(logit - m);
    float ssum = e;
#pragma unroll
    for (int off = 32; off > 0; off >>= 1) ssum += __shfl_xor(ssum, off);
    float wgt = e / ssum;
    float o0 = wgt * E0, o1 = wgt * E1;
#pragma unroll
    for (int off = 32; off > 0; off >>= 1) {
      o0 += __shfl_xor(o0, off);
      o1 += __shfl_xor(o1, off);
    }
    if (r == 0) {
      out[b * 4 + 2] = o0;
      out[b * 4 + 3] = o1;
    }
  }
}

// ---------------------------------------------------------------------------
extern "C" void kernel_launch(void* const* d_in, const int* in_sizes, int n_in,
                              void* d_out, int out_size, void* d_ws, size_t ws_size,
                              hipStream_t stream) {
  const float* ego_y = (const float*)d_in[0];
  const float* Pn    = (const float*)d_in[1];
  const float* Pego  = (const float*)d_in[2];
  const float* Vn    = (const float*)d_in[3];
  const float* Vego  = (const float*)d_in[4];
  const float* Cn    = (const float*)d_in[5];
  const float* W_sel = (const float*)d_in[6];
  const float* b_sel = (const float*)d_in[7];
  const float* W_s0  = (const float*)d_in[8];
  const float* b_s0  = (const float*)d_in[9];
  const float* W_map = (const float*)d_in[10];
  const float* b_map = (const float*)d_in[11];
  const float* W_efc = (const float*)d_in[12];
  const float* b_efc = (const float*)d_in[13];
  const float* W_s1  = (const float*)d_in[14];
  const float* b_s1  = (const float*)d_in[15];
  const float* W1    = (const float*)d_in[16];
  const float* b1    = (const float*)d_in[17];
  const float* W2    = (const float*)d_in[18];
  const float* b2    = (const float*)d_in[19];
  const float* W3    = (const float*)d_in[20];
  const float* b3    = (const float*)d_in[21];
  const float* Ww    = (const float*)d_in[22];
  const float* bw    = (const float*)d_in[23];
  float* out = (float*)d_out;

  short* W1F = (short*)d_ws;          // 2 planes x 32768 shorts = 128 KB
  short* W2F = W1F + 65536;           // 2 planes x 32768 shorts = 128 KB

  w_prep_kernel<<<16, 256, 0, stream>>>(W1, W2, W1F, W2F);
  er_kernel<<<NB / 32, 256, 0, stream>>>(ego_y, W_sel, b_sel, W_s0, b_s0,
                                         W_map, b_map, W_efc, b_efc, out);
  en_kernel<<<NB, 512, 0, stream>>>(Pn, Pego, Vn, Vego, Cn, W_s1, b_s1,
                                    b1, b2, W3, b3, Ww, bw, W1F, W2F, out);
}